// Round 18
// baseline (1968.625 us; speedup 1.0000x reference)
//
#include <hip/hip_runtime.h>
#include <hip/hip_bf16.h>

#define BIN_SHIFT 8                  // 256 nodes per bin
#define BIN_NODES 256
#define BIN_CAP   8192
#define EPT       16                 // edges per thread in binB (512-thread blocks -> 8192/blk)

typedef float v2f __attribute__((ext_vector_type(2)));

__device__ __forceinline__ float leaky02(float a) { return fmaxf(a, 0.2f * a); }
__device__ __forceinline__ unsigned short f2bf(float f) {
    __hip_bfloat16 h = __float2bfloat16(f);
    return *(unsigned short*)&h;
}
__device__ __forceinline__ float bflo(unsigned u) { return __uint_as_float(u << 16); }
__device__ __forceinline__ float bfhi(unsigned u) { return __uint_as_float(u & 0xffff0000u); }
__device__ __forceinline__ v2f bf2(unsigned u) {
    v2f r; r.x = __uint_as_float(u << 16); r.y = __uint_as_float(u & 0xffff0000u); return r;
}

// ---------- K1: grid-partitioned {binB | gemm1+att} ----------
// gemm path: 128-row tile, 2r x 8c per thread (8 cols = one head -> lane-local att dot),
// K staged in quarters of 32. LDS = 32KB (W) + 18KB (xs) + 2KB -> 3 blocks/CU.
__global__ __launch_bounds__(512) void k1_kernel(const float* __restrict__ x,
                                                 const float* __restrict__ W,
                                                 const float* __restrict__ a1d,
                                                 const int* __restrict__ ei,
                                                 __hip_bfloat16* __restrict__ xh,
                                                 float* __restrict__ adst,
                                                 int* __restrict__ cur,
                                                 unsigned* __restrict__ binned,
                                                 int N, int E, int Etot, int NB, int NBB) {
    __shared__ float ws[128 * 64];
    __shared__ float xs[128][36];
    __shared__ int bcnt[512];
    int tid = threadIdx.x;
    if (blockIdx.x < NBB) {
        // ---------------- binB path (dst staged in LDS, aliases ws) ----------------
        int* dstbuf = (int*)ws;
        bcnt[tid] = 0;
        __syncthreads();
        long long base = (long long)blockIdx.x * 512 * EPT;
#pragma unroll 4
        for (int i = 0; i < EPT; ++i) {
            long long e = base + i * 512 + tid;
            if (e < Etot) {
                int dst = (e < E) ? ei[E + e] : (int)(e - E);
                dstbuf[i * 512 + tid] = dst;
                atomicAdd(&bcnt[dst >> BIN_SHIFT], 1);
            }
        }
        __syncthreads();
        for (int b = tid; b < NB; b += 512) {
            int c = bcnt[b];
            bcnt[b] = c ? atomicAdd(&cur[b], c) : 0;
        }
        __syncthreads();
#pragma unroll 4
        for (int i = 0; i < EPT; ++i) {
            long long e = base + i * 512 + tid;
            if (e < Etot) {
                int dst = dstbuf[i * 512 + tid];
                int src = (e < E) ? ei[e] : dst;
                int bin = dst >> BIN_SHIFT;
                int p = atomicAdd(&bcnt[bin], 1);
                if (p < BIN_CAP)
                    binned[(size_t)bin * BIN_CAP + p] = ((unsigned)(dst & (BIN_NODES - 1)) << 24) | (unsigned)src;
            }
        }
        return;
    }
    // ---------------- gemm path ----------------
    int gb = blockIdx.x - NBB;
    for (int i = tid; i < 2048; i += 512) ((float4*)ws)[i] = ((const float4*)W)[i];
    int row0 = gb * 128;
    int tc = tid & 7, trg = tid >> 3;      // cols tc*8..+7, rows trg*2, trg*2+1
    float acc0[8] = {}, acc1[8] = {};
#pragma unroll
    for (int q = 0; q < 4; ++q) {
        __syncthreads();   // first: covers W-stage; later: protects xs reuse
        for (int i = tid; i < 1024; i += 512) {
            int r = i >> 3, c4 = i & 7;
            int row = row0 + r;
            float4 v = make_float4(0.f, 0.f, 0.f, 0.f);
            if (row < N) v = ((const float4*)x)[(size_t)row * 32 + q * 8 + c4];
            *(float4*)&xs[r][c4 * 4] = v;
        }
        __syncthreads();
#pragma unroll
        for (int kt = 0; kt < 8; ++kt) {
            float4 a0 = *(const float4*)&xs[trg * 2][kt * 4];
            float4 a1 = *(const float4*)&xs[trg * 2 + 1][kt * 4];
            float a0j[4] = {a0.x, a0.y, a0.z, a0.w};
            float a1j[4] = {a1.x, a1.y, a1.z, a1.w};
#pragma unroll
            for (int j = 0; j < 4; ++j) {
                const float* bp = &ws[(q * 32 + kt * 4 + j) * 64 + tc * 8];
                float4 b0 = *(const float4*)bp;
                float4 b1v = *(const float4*)(bp + 4);
                float bb[8] = {b0.x, b0.y, b0.z, b0.w, b1v.x, b1v.y, b1v.z, b1v.w};
#pragma unroll
                for (int c = 0; c < 8; ++c) {
                    acc0[c] += a0j[j] * bb[c];
                    acc1[c] += a1j[j] * bb[c];
                }
            }
        }
    }
    // epilogue: 8 cols = head tc -> lane-local att-dst dot, no shuffles
    float4 dA = ((const float4*)a1d)[tc * 2], dB = ((const float4*)a1d)[tc * 2 + 1];
    float dw[8] = {dA.x, dA.y, dA.z, dA.w, dB.x, dB.y, dB.z, dB.w};
    int rowA = row0 + trg * 2;
    if (rowA < N) {
        uint4 o;
        o.x = (unsigned)f2bf(acc0[0]) | ((unsigned)f2bf(acc0[1]) << 16);
        o.y = (unsigned)f2bf(acc0[2]) | ((unsigned)f2bf(acc0[3]) << 16);
        o.z = (unsigned)f2bf(acc0[4]) | ((unsigned)f2bf(acc0[5]) << 16);
        o.w = (unsigned)f2bf(acc0[6]) | ((unsigned)f2bf(acc0[7]) << 16);
        *(uint4*)(xh + (size_t)rowA * 64 + tc * 8) = o;
        float dp = acc0[0] * dw[0] + acc0[1] * dw[1] + acc0[2] * dw[2] + acc0[3] * dw[3]
                 + acc0[4] * dw[4] + acc0[5] * dw[5] + acc0[6] * dw[6] + acc0[7] * dw[7];
        adst[rowA * 8 + tc] = dp;
    }
    int rowB = rowA + 1;
    if (rowB < N) {
        uint4 o;
        o.x = (unsigned)f2bf(acc1[0]) | ((unsigned)f2bf(acc1[1]) << 16);
        o.y = (unsigned)f2bf(acc1[2]) | ((unsigned)f2bf(acc1[3]) << 16);
        o.z = (unsigned)f2bf(acc1[4]) | ((unsigned)f2bf(acc1[5]) << 16);
        o.w = (unsigned)f2bf(acc1[6]) | ((unsigned)f2bf(acc1[7]) << 16);
        *(uint4*)(xh + (size_t)rowB * 64 + tc * 8) = o;
        float dp = acc1[0] * dw[0] + acc1[1] * dw[1] + acc1[2] * dw[2] + acc1[3] * dw[3]
                 + acc1[4] * dw[4] + acc1[5] * dw[5] + acc1[6] * dw[6] + acc1[7] * dw[7];
        adst[rowB * 8 + tc] = dp;
    }
}

// ---------- binC: per-bin -> rowptr + in-bin scatter to esrc ----------
__global__ __launch_bounds__(256) void binC_kernel(const int* __restrict__ cur,
                                                   const unsigned* __restrict__ binned,
                                                   int* __restrict__ rowptr,
                                                   int* __restrict__ esrc,
                                                   int N, int Etot, int NB) {
    int bin = blockIdx.x;
    int tid = threadIdx.x;
    __shared__ int psum[256];
    __shared__ int sc[256];
    __shared__ int ndc[256];
    int s = 0;
    for (int i = tid; i < bin; i += 256) s += cur[i];
    psum[tid] = s;
    __syncthreads();
    for (int off = 128; off > 0; off >>= 1) {
        if (tid < off) psum[tid] += psum[tid + off];
        __syncthreads();
    }
    int bbase = psum[0];
    int cnt = cur[bin];
    ndc[tid] = 0;
    __syncthreads();
    const unsigned* bp = binned + (size_t)bin * BIN_CAP;
    for (int i = tid; i < cnt; i += 256)
        atomicAdd(&ndc[bp[i] >> 24], 1);
    __syncthreads();
    int v = ndc[tid];
    sc[tid] = v;
    __syncthreads();
    for (int off = 1; off < 256; off <<= 1) {
        int t = (tid >= off) ? sc[tid - off] : 0;
        __syncthreads();
        sc[tid] += t;
        __syncthreads();
    }
    int excl = sc[tid] - v;
    int node = bin * BIN_NODES + tid;
    if (node < N) rowptr[node] = bbase + excl;
    if (bin == NB - 1 && tid == 0) rowptr[N] = Etot;
    ndc[tid] = excl;
    __syncthreads();
    for (int i = tid; i < cnt; i += 256) {
        unsigned w = bp[i];
        int p = atomicAdd(&ndc[w >> 24], 1);
        esrc[bbase + p] = (int)(w & 0xFFFFFFu);
    }
}

// ---------- layer-1 aggregate (a_src recomputed from xh row) + bias + ELU -> h1 ----------
__global__ __launch_bounds__(256) void agg1_kernel(const int* __restrict__ rowptr,
                                                   const int* __restrict__ esrc,
                                                   const float* __restrict__ a1s,
                                                   const float* __restrict__ adst,
                                                   const __hip_bfloat16* __restrict__ xh,
                                                   const float* __restrict__ b1,
                                                   __hip_bfloat16* __restrict__ h1, int N) {
    int node = blockIdx.x * 4 + (threadIdx.x >> 6);
    if (node >= N) return;
    int lane = threadIdx.x & 63;
    unsigned slot = (unsigned)(lane >> 3), h = (unsigned)(lane & 7);
    float adh = adst[(unsigned)node * 8u + h];
    const float* wsh = a1s + h * 8u;
    v2f w01 = {wsh[0], wsh[1]}, w23 = {wsh[2], wsh[3]};
    v2f w45 = {wsh[4], wsh[5]}, w67 = {wsh[6], wsh[7]};
    unsigned start = (unsigned)rowptr[node];
    int len = rowptr[node + 1] - (int)start;
    const uint4* xh4 = (const uint4*)xh;
    float d = 0.f;
    v2f acc0 = {0.f, 0.f}, acc1 = {0.f, 0.f}, acc2 = {0.f, 0.f}, acc3 = {0.f, 0.f};
    for (int kb = 0; kb < len; kb += 32) {
        int k0 = kb + (int)slot;
        bool ok0 = k0 < len, ok1 = k0 + 8 < len, ok2 = k0 + 16 < len, ok3 = k0 + 24 < len;
        unsigned s0 = ok0 ? (unsigned)esrc[start + k0] : 0u;
        unsigned s1 = ok1 ? (unsigned)esrc[start + k0 + 8] : 0u;
        unsigned s2 = ok2 ? (unsigned)esrc[start + k0 + 16] : 0u;
        unsigned s3 = ok3 ? (unsigned)esrc[start + k0 + 24] : 0u;
        uint4 u0 = xh4[s0 * 8u + h];
        uint4 u1 = xh4[s1 * 8u + h];
        uint4 u2 = xh4[s2 * 8u + h];
        uint4 u3 = xh4[s3 * 8u + h];
        v2f v00 = bf2(u0.x), v01 = bf2(u0.y), v02 = bf2(u0.z), v03 = bf2(u0.w);
        v2f v10 = bf2(u1.x), v11 = bf2(u1.y), v12 = bf2(u1.z), v13 = bf2(u1.w);
        v2f v20 = bf2(u2.x), v21 = bf2(u2.y), v22 = bf2(u2.z), v23 = bf2(u2.w);
        v2f v30 = bf2(u3.x), v31 = bf2(u3.y), v32 = bf2(u3.z), v33 = bf2(u3.w);
        v2f av0 = v00 * w01 + v01 * w23 + v02 * w45 + v03 * w67;
        v2f av1 = v10 * w01 + v11 * w23 + v12 * w45 + v13 * w67;
        v2f av2 = v20 * w01 + v21 * w23 + v22 * w45 + v23 * w67;
        v2f av3 = v30 * w01 + v31 * w23 + v32 * w45 + v33 * w67;
        float p0 = ok0 ? __expf(leaky02(av0.x + av0.y + adh)) : 0.f;
        float p1 = ok1 ? __expf(leaky02(av1.x + av1.y + adh)) : 0.f;
        float p2 = ok2 ? __expf(leaky02(av2.x + av2.y + adh)) : 0.f;
        float p3 = ok3 ? __expf(leaky02(av3.x + av3.y + adh)) : 0.f;
        d += (p0 + p1) + (p2 + p3);
        acc0 += v00 * p0; acc1 += v01 * p0; acc2 += v02 * p0; acc3 += v03 * p0;
        acc0 += v10 * p1; acc1 += v11 * p1; acc2 += v12 * p1; acc3 += v13 * p1;
        acc0 += v20 * p2; acc1 += v21 * p2; acc2 += v22 * p2; acc3 += v23 * p2;
        acc0 += v30 * p3; acc1 += v31 * p3; acc2 += v32 * p3; acc3 += v33 * p3;
    }
    // reduce over the 8 slot-lanes (lane bits 3..5)
#pragma unroll
    for (int off = 8; off < 64; off <<= 1) {
        d += __shfl_xor(d, off);
        acc0.x += __shfl_xor(acc0.x, off); acc0.y += __shfl_xor(acc0.y, off);
        acc1.x += __shfl_xor(acc1.x, off); acc1.y += __shfl_xor(acc1.y, off);
        acc2.x += __shfl_xor(acc2.x, off); acc2.y += __shfl_xor(acc2.y, off);
        acc3.x += __shfl_xor(acc3.x, off); acc3.y += __shfl_xor(acc3.y, off);
    }
    float vals[8] = {acc0.x, acc0.y, acc1.x, acc1.y, acc2.x, acc2.y, acc3.x, acc3.y};
    float hv = vals[0];
#pragma unroll
    for (int c = 1; c < 8; ++c) hv = ((int)slot == c) ? vals[c] : hv;
    int f = (int)(h * 8u + slot);
    hv = hv / (d + 1e-16f) + b1[f];
    hv = hv > 0.f ? hv : __expf(hv) - 1.0f;          // ELU
    // permute so lane stores feature f' = lane (contiguous 2B stores)
    float hvp = __shfl(hv, ((lane & 7) << 3) | (lane >> 3));
    h1[(unsigned)node * 64u + (unsigned)lane] = __float2bfloat16(hvp);
}

// ---------- layer-2 GEMM: h1[N,64](bf16) @ W2[64,8] + adst2 scalar ----------
__global__ __launch_bounds__(256) void gemm2h_kernel(const __hip_bfloat16* __restrict__ h1,
                                                     const float* __restrict__ W2,
                                                     const float* __restrict__ a2d,
                                                     __hip_bfloat16* __restrict__ xh2,
                                                     float* __restrict__ adst2, int N) {
    __shared__ float w2s[512];
    __shared__ float aa[8];
    int tid = threadIdx.x;
    for (int i = tid; i < 512; i += 256) w2s[i] = W2[i];
    if (tid < 8) aa[tid] = a2d[tid];
    __syncthreads();
    unsigned n = blockIdx.x * 256u + (unsigned)tid;
    if (n >= (unsigned)N) return;
    const uint4* hp = (const uint4*)h1 + n * 8u;
    float q[8] = {};
#pragma unroll
    for (int j = 0; j < 8; ++j) {
        uint4 u = hp[j];
        float hv[8] = {bflo(u.x), bfhi(u.x), bflo(u.y), bfhi(u.y),
                       bflo(u.z), bfhi(u.z), bflo(u.w), bfhi(u.w)};
#pragma unroll
        for (int e = 0; e < 8; ++e) {
            int f = j * 8 + e;
            float4 wa = *(const float4*)&w2s[f * 8];
            float4 wb = *(const float4*)&w2s[f * 8 + 4];
            q[0] += hv[e] * wa.x; q[1] += hv[e] * wa.y;
            q[2] += hv[e] * wa.z; q[3] += hv[e] * wa.w;
            q[4] += hv[e] * wb.x; q[5] += hv[e] * wb.y;
            q[6] += hv[e] * wb.z; q[7] += hv[e] * wb.w;
        }
    }
    uint4 o;
    o.x = (unsigned)f2bf(q[0]) | ((unsigned)f2bf(q[1]) << 16);
    o.y = (unsigned)f2bf(q[2]) | ((unsigned)f2bf(q[3]) << 16);
    o.z = (unsigned)f2bf(q[4]) | ((unsigned)f2bf(q[5]) << 16);
    o.w = (unsigned)f2bf(q[6]) | ((unsigned)f2bf(q[7]) << 16);
    *((uint4*)xh2 + n) = o;
    float d2 = 0.f;
#pragma unroll
    for (int c = 0; c < 8; ++c) d2 += q[c] * aa[c];
    adst2[n] = d2;
}

// ---------- layer-2 aggregate (a_src2 recomputed) + bias + fused mean-pool ----------
__global__ __launch_bounds__(256) void agg2_pool_kernel(const int* __restrict__ rowptr,
                                                        const int* __restrict__ esrc,
                                                        const float* __restrict__ a2s,
                                                        const float* __restrict__ adst2,
                                                        const __hip_bfloat16* __restrict__ xh2,
                                                        const float* __restrict__ b2,
                                                        const int* __restrict__ batch,
                                                        float* __restrict__ pool,
                                                        float* __restrict__ cnt, int N, int B) {
    __shared__ float ps[64 * 8];
    __shared__ float cs[64];
    int tid = threadIdx.x;
    for (int i = tid; i < 512; i += 256) ps[i] = 0.f;
    if (tid < 64) cs[tid] = 0.f;
    __syncthreads();
    int node = blockIdx.x * 32 + (tid >> 3);
    int slot = tid & 7;
    if (node < N) {
        float adh = adst2[node];
        v2f w01 = {a2s[0], a2s[1]}, w23 = {a2s[2], a2s[3]};
        v2f w45 = {a2s[4], a2s[5]}, w67 = {a2s[6], a2s[7]};
        unsigned start = (unsigned)rowptr[node];
        int len = rowptr[node + 1] - (int)start;
        const uint4* x4 = (const uint4*)xh2;
        float d = 0.f;
        v2f acc0 = {0.f, 0.f}, acc1 = {0.f, 0.f}, acc2 = {0.f, 0.f}, acc3 = {0.f, 0.f};
        for (int kb = 0; kb < len; kb += 32) {
            int k0 = kb + slot;
            bool ok0 = k0 < len, ok1 = k0 + 8 < len, ok2 = k0 + 16 < len, ok3 = k0 + 24 < len;
            unsigned s0 = ok0 ? (unsigned)esrc[start + k0] : 0u;
            unsigned s1 = ok1 ? (unsigned)esrc[start + k0 + 8] : 0u;
            unsigned s2 = ok2 ? (unsigned)esrc[start + k0 + 16] : 0u;
            unsigned s3 = ok3 ? (unsigned)esrc[start + k0 + 24] : 0u;
            uint4 u0 = x4[s0];
            uint4 u1 = x4[s1];
            uint4 u2 = x4[s2];
            uint4 u3 = x4[s3];
            v2f v00 = bf2(u0.x), v01 = bf2(u0.y), v02 = bf2(u0.z), v03 = bf2(u0.w);
            v2f v10 = bf2(u1.x), v11 = bf2(u1.y), v12 = bf2(u1.z), v13 = bf2(u1.w);
            v2f v20 = bf2(u2.x), v21 = bf2(u2.y), v22 = bf2(u2.z), v23 = bf2(u2.w);
            v2f v30 = bf2(u3.x), v31 = bf2(u3.y), v32 = bf2(u3.z), v33 = bf2(u3.w);
            v2f av0 = v00 * w01 + v01 * w23 + v02 * w45 + v03 * w67;
            v2f av1 = v10 * w01 + v11 * w23 + v12 * w45 + v13 * w67;
            v2f av2 = v20 * w01 + v21 * w23 + v22 * w45 + v23 * w67;
            v2f av3 = v30 * w01 + v31 * w23 + v32 * w45 + v33 * w67;
            float p0 = ok0 ? __expf(leaky02(av0.x + av0.y + adh)) : 0.f;
            float p1 = ok1 ? __expf(leaky02(av1.x + av1.y + adh)) : 0.f;
            float p2 = ok2 ? __expf(leaky02(av2.x + av2.y + adh)) : 0.f;
            float p3 = ok3 ? __expf(leaky02(av3.x + av3.y + adh)) : 0.f;
            d += (p0 + p1) + (p2 + p3);
            acc0 += v00 * p0; acc1 += v01 * p0; acc2 += v02 * p0; acc3 += v03 * p0;
            acc0 += v10 * p1; acc1 += v11 * p1; acc2 += v12 * p1; acc3 += v13 * p1;
            acc0 += v20 * p2; acc1 += v21 * p2; acc2 += v22 * p2; acc3 += v23 * p2;
            acc0 += v30 * p3; acc1 += v31 * p3; acc2 += v32 * p3; acc3 += v33 * p3;
        }
#pragma unroll
        for (int off = 1; off < 8; off <<= 1) {
            d += __shfl_xor(d, off);
            acc0.x += __shfl_xor(acc0.x, off); acc0.y += __shfl_xor(acc0.y, off);
            acc1.x += __shfl_xor(acc1.x, off); acc1.y += __shfl_xor(acc1.y, off);
            acc2.x += __shfl_xor(acc2.x, off); acc2.y += __shfl_xor(acc2.y, off);
            acc3.x += __shfl_xor(acc3.x, off); acc3.y += __shfl_xor(acc3.y, off);
        }
        float vals[8] = {acc0.x, acc0.y, acc1.x, acc1.y, acc2.x, acc2.y, acc3.x, acc3.y};
        float v = vals[0];
#pragma unroll
        for (int c = 1; c < 8; ++c) v = (slot == c) ? vals[c] : v;
        v = v / (d + 1e-16f) + b2[slot];
        int b = batch[node];
        atomicAdd(&ps[b * 8 + slot], v);
        if (slot == 0) atomicAdd(&cs[b], 1.0f);
    }
    __syncthreads();
    for (int i = tid; i < 512; i += 256)
        if (ps[i] != 0.f) atomicAdd(&pool[i], ps[i]);
    if (tid < 64 && cs[tid] != 0.f) atomicAdd(&cnt[tid], cs[tid]);
}

__global__ __launch_bounds__(256) void final_kernel(const float* __restrict__ pool,
                                                    const float* __restrict__ cnt,
                                                    float* __restrict__ out, int B) {
    int idx = blockIdx.x * 256 + threadIdx.x;
    if (idx >= B * 8) return;
    out[idx] = pool[idx] / fmaxf(cnt[idx >> 3], 1.0f);
}

extern "C" void kernel_launch(void* const* d_in, const int* in_sizes, int n_in,
                              void* d_out, int out_size, void* d_ws, size_t ws_size,
                              hipStream_t stream) {
    const float* x   = (const float*)d_in[0];
    const int*   ei  = (const int*)d_in[1];
    const int*   bat = (const int*)d_in[2];
    const float* W1  = (const float*)d_in[3];
    const float* a1s = (const float*)d_in[4];
    const float* a1d = (const float*)d_in[5];
    const float* b1  = (const float*)d_in[6];
    const float* W2  = (const float*)d_in[7];
    const float* a2s = (const float*)d_in[8];
    const float* a2d = (const float*)d_in[9];
    const float* b2  = (const float*)d_in[10];
    float* out = (float*)d_out;

    const int N = in_sizes[0] / 128;
    const int E = in_sizes[1] / 2;
    const int B = out_size / 8;
    const int Etot = E + N;
    const int NB = (N + BIN_NODES - 1) / BIN_NODES;
    const int NBB = (Etot + 512 * EPT - 1) / (512 * EPT);   // binB blocks
    const int NG = (N + 127) / 128;                         // gemm blocks

    // ---- workspace layout (float slots) ----
    float* wsp = (float*)d_ws;
    __hip_bfloat16* xh1 = (__hip_bfloat16*)wsp;                       // 64N bf16 = 32N fl
    float* adst1  = wsp + (size_t)N * 32;                             // 8N
    __hip_bfloat16* h1 = (__hip_bfloat16*)(adst1 + (size_t)N * 8);    // 64N bf16 = 32N fl
    __hip_bfloat16* xh2 = (__hip_bfloat16*)(adst1 + (size_t)N * 40);  // 8N bf16 = 4N fl
    float* adst2  = adst1 + (size_t)N * 44;                           // N
    int*   rowptr = (int*)(adst2 + (size_t)N);                        // N+1 (+pad)
    int*   esrc   = rowptr + (size_t)N + 8;                           // Etot
    unsigned* binned = (unsigned*)(esrc + (size_t)Etot);              // NB*BIN_CAP
    // ---- zero-init region ----
    int*   cur    = (int*)(binned + (size_t)NB * BIN_CAP);            // NB
    float* pool   = (float*)(cur + NB);                               // 8B
    float* cnt    = pool + (size_t)B * 8;                             // B
    size_t zbytes = ((size_t)NB + 9 * (size_t)B) * 4;
    hipMemsetAsync(cur, 0, zbytes, stream);

    k1_kernel<<<dim3(NBB + NG), dim3(512), 0, stream>>>(x, W1, a1d, ei,
                                                        xh1, adst1,
                                                        cur, binned, N, E, Etot, NB, NBB);
    binC_kernel<<<dim3(NB), dim3(256), 0, stream>>>(cur, binned, rowptr, esrc, N, Etot, NB);
    agg1_kernel<<<dim3((N + 3) / 4), dim3(256), 0, stream>>>(rowptr, esrc, a1s, adst1, xh1, b1, h1, N);
    gemm2h_kernel<<<dim3((N + 255) / 256), dim3(256), 0, stream>>>(h1, W2, a2d, xh2, adst2, N);
    agg2_pool_kernel<<<dim3((N + 31) / 32), dim3(256), 0, stream>>>(rowptr, esrc, a2s, adst2,
                                                                    xh2, b2, bat, pool, cnt, N, B);
    final_kernel<<<dim3((B * 8 + 255) / 256), dim3(256), 0, stream>>>(pool, cnt, out, B);
}

// Round 19
// 147.091 us; speedup vs baseline: 13.3838x; 13.3838x over previous
//
#include <hip/hip_runtime.h>
#include <hip/hip_bf16.h>

#define BIN_SHIFT 8                  // 256 nodes per bin
#define BIN_NODES 256
#define BIN_CAP   8192
#define EPT       16                 // edges per thread in binB (512-thread blocks -> 8192/blk)

typedef float v2f __attribute__((ext_vector_type(2)));

__device__ __forceinline__ float leaky02(float a) { return fmaxf(a, 0.2f * a); }
__device__ __forceinline__ unsigned short f2bf(float f) {
    __hip_bfloat16 h = __float2bfloat16(f);
    return *(unsigned short*)&h;
}
__device__ __forceinline__ float bflo(unsigned u) { return __uint_as_float(u << 16); }
__device__ __forceinline__ float bfhi(unsigned u) { return __uint_as_float(u & 0xffff0000u); }
__device__ __forceinline__ v2f bf2(unsigned u) {
    v2f r; r.x = __uint_as_float(u << 16); r.y = __uint_as_float(u & 0xffff0000u); return r;
}

// ---------- K1: grid-partitioned {binB | gemm1+att} (R15-proven form) ----------
// gemm path: 64-row tile, x staged in LDS in two 64-col halves, 2r x 4c per thread
__global__ __launch_bounds__(512) void k1_kernel(const float* __restrict__ x,
                                                 const float* __restrict__ W,
                                                 const float* __restrict__ a1d,
                                                 const int* __restrict__ ei,
                                                 __hip_bfloat16* __restrict__ xh,
                                                 float* __restrict__ adst,
                                                 int* __restrict__ cur,
                                                 unsigned* __restrict__ binned,
                                                 int N, int E, int Etot, int NB, int NBB) {
    __shared__ float ws[128 * 64];
    __shared__ float xs[64][66];
    __shared__ int bcnt[512];
    int tid = threadIdx.x;
    if (blockIdx.x < NBB) {
        // ---------------- binB path ----------------
        bcnt[tid] = 0;
        __syncthreads();
        long long base = (long long)blockIdx.x * 512 * EPT;
#pragma unroll 4
        for (int i = 0; i < EPT; ++i) {
            long long e = base + i * 512 + tid;
            if (e < Etot) {
                int dst = (e < E) ? ei[E + e] : (int)(e - E);
                atomicAdd(&bcnt[dst >> BIN_SHIFT], 1);
            }
        }
        __syncthreads();
        for (int b = tid; b < NB; b += 512) {
            int c = bcnt[b];
            bcnt[b] = c ? atomicAdd(&cur[b], c) : 0;
        }
        __syncthreads();
#pragma unroll 4
        for (int i = 0; i < EPT; ++i) {
            long long e = base + i * 512 + tid;
            if (e < Etot) {
                int src, dst;
                if (e < E) { src = ei[e]; dst = ei[E + e]; }
                else       { src = dst = (int)(e - E); }
                int bin = dst >> BIN_SHIFT;
                int p = atomicAdd(&bcnt[bin], 1);
                if (p < BIN_CAP)
                    binned[(size_t)bin * BIN_CAP + p] = ((unsigned)(dst & (BIN_NODES - 1)) << 24) | (unsigned)src;
            }
        }
        return;
    }
    // ---------------- gemm path ----------------
    int gb = blockIdx.x - NBB;
    for (int i = tid; i < 2048; i += 512) ((float4*)ws)[i] = ((const float4*)W)[i];
    int row0 = gb * 64;
    int tc = tid & 15, tr = tid >> 4;      // tr 0..31 -> rows 2tr,2tr+1; cols 4tc..
    float acc[2][4] = {};
#pragma unroll
    for (int half = 0; half < 2; ++half) {
        __syncthreads();   // first: covers W-stage; later: protects xs reuse
        for (int i = tid; i < 1024; i += 512) {
            int r = i >> 4, c4 = i & 15;
            int row = row0 + r;
            float4 v = make_float4(0.f, 0.f, 0.f, 0.f);
            if (row < N) v = ((const float4*)x)[(size_t)row * 32 + half * 16 + c4];
            float* p = &xs[r][c4 * 4];
            p[0] = v.x; p[1] = v.y; p[2] = v.z; p[3] = v.w;
        }
        __syncthreads();
#pragma unroll 4
        for (int k = 0; k < 64; ++k) {
            float a0 = xs[tr * 2][k];
            float a1 = xs[tr * 2 + 1][k];
            float4 b = *(const float4*)&ws[(half * 64 + k) * 64 + tc * 4];
            acc[0][0] += a0 * b.x; acc[0][1] += a0 * b.y; acc[0][2] += a0 * b.z; acc[0][3] += a0 * b.w;
            acc[1][0] += a1 * b.x; acc[1][1] += a1 * b.y; acc[1][2] += a1 * b.z; acc[1][3] += a1 * b.w;
        }
    }
    float4 dv = ((const float4*)a1d)[tc];
    int head = tc >> 1;
#pragma unroll
    for (int r = 0; r < 2; ++r) {
        int row = row0 + tr * 2 + r;
        if (row < N) {
            uint2 o;
            o.x = (unsigned)f2bf(acc[r][0]) | ((unsigned)f2bf(acc[r][1]) << 16);
            o.y = (unsigned)f2bf(acc[r][2]) | ((unsigned)f2bf(acc[r][3]) << 16);
            *(uint2*)(xh + (size_t)row * 64 + tc * 4) = o;
        }
        float dp = acc[r][0] * dv.x + acc[r][1] * dv.y + acc[r][2] * dv.z + acc[r][3] * dv.w;
        dp += __shfl_xor(dp, 1);
        if (!(tc & 1) && row < N) adst[row * 8 + head] = dp;
    }
}

// ---------- binC: per-bin -> rowptr + in-bin scatter to esrc ----------
__global__ __launch_bounds__(256) void binC_kernel(const int* __restrict__ cur,
                                                   const unsigned* __restrict__ binned,
                                                   int* __restrict__ rowptr,
                                                   int* __restrict__ esrc,
                                                   int N, int Etot, int NB) {
    int bin = blockIdx.x;
    int tid = threadIdx.x;
    __shared__ int psum[256];
    __shared__ int sc[256];
    __shared__ int ndc[256];
    int s = 0;
    for (int i = tid; i < bin; i += 256) s += cur[i];
    psum[tid] = s;
    __syncthreads();
    for (int off = 128; off > 0; off >>= 1) {
        if (tid < off) psum[tid] += psum[tid + off];
        __syncthreads();
    }
    int bbase = psum[0];
    int cnt = cur[bin];
    ndc[tid] = 0;
    __syncthreads();
    const unsigned* bp = binned + (size_t)bin * BIN_CAP;
    for (int i = tid; i < cnt; i += 256)
        atomicAdd(&ndc[bp[i] >> 24], 1);
    __syncthreads();
    int v = ndc[tid];
    sc[tid] = v;
    __syncthreads();
    for (int off = 1; off < 256; off <<= 1) {
        int t = (tid >= off) ? sc[tid - off] : 0;
        __syncthreads();
        sc[tid] += t;
        __syncthreads();
    }
    int excl = sc[tid] - v;
    int node = bin * BIN_NODES + tid;
    if (node < N) rowptr[node] = bbase + excl;
    if (bin == NB - 1 && tid == 0) rowptr[N] = Etot;
    ndc[tid] = excl;
    __syncthreads();
    for (int i = tid; i < cnt; i += 256) {
        unsigned w = bp[i];
        int p = atomicAdd(&ndc[w >> 24], 1);
        esrc[bbase + p] = (int)(w & 0xFFFFFFu);
    }
}

// ---------- layer-1 aggregate (a_src recomputed from xh row) + bias + ELU -> h1 ----------
__global__ __launch_bounds__(256) void agg1_kernel(const int* __restrict__ rowptr,
                                                   const int* __restrict__ esrc,
                                                   const float* __restrict__ a1s,
                                                   const float* __restrict__ adst,
                                                   const __hip_bfloat16* __restrict__ xh,
                                                   const float* __restrict__ b1,
                                                   __hip_bfloat16* __restrict__ h1, int N) {
    int node = blockIdx.x * 4 + (threadIdx.x >> 6);
    if (node >= N) return;
    int lane = threadIdx.x & 63;
    unsigned slot = (unsigned)(lane >> 3), h = (unsigned)(lane & 7);
    float adh = adst[(unsigned)node * 8u + h];
    const float* wsh = a1s + h * 8u;
    v2f w01 = {wsh[0], wsh[1]}, w23 = {wsh[2], wsh[3]};
    v2f w45 = {wsh[4], wsh[5]}, w67 = {wsh[6], wsh[7]};
    unsigned start = (unsigned)rowptr[node];
    int len = rowptr[node + 1] - (int)start;
    const uint4* xh4 = (const uint4*)xh;
    float d = 0.f;
    v2f acc0 = {0.f, 0.f}, acc1 = {0.f, 0.f}, acc2 = {0.f, 0.f}, acc3 = {0.f, 0.f};
    for (int kb = 0; kb < len; kb += 32) {
        int k0 = kb + (int)slot;
        bool ok0 = k0 < len, ok1 = k0 + 8 < len, ok2 = k0 + 16 < len, ok3 = k0 + 24 < len;
        unsigned s0 = ok0 ? (unsigned)esrc[start + k0] : 0u;
        unsigned s1 = ok1 ? (unsigned)esrc[start + k0 + 8] : 0u;
        unsigned s2 = ok2 ? (unsigned)esrc[start + k0 + 16] : 0u;
        unsigned s3 = ok3 ? (unsigned)esrc[start + k0 + 24] : 0u;
        uint4 u0 = xh4[s0 * 8u + h];
        uint4 u1 = xh4[s1 * 8u + h];
        uint4 u2 = xh4[s2 * 8u + h];
        uint4 u3 = xh4[s3 * 8u + h];
        v2f v00 = bf2(u0.x), v01 = bf2(u0.y), v02 = bf2(u0.z), v03 = bf2(u0.w);
        v2f v10 = bf2(u1.x), v11 = bf2(u1.y), v12 = bf2(u1.z), v13 = bf2(u1.w);
        v2f v20 = bf2(u2.x), v21 = bf2(u2.y), v22 = bf2(u2.z), v23 = bf2(u2.w);
        v2f v30 = bf2(u3.x), v31 = bf2(u3.y), v32 = bf2(u3.z), v33 = bf2(u3.w);
        v2f av0 = v00 * w01 + v01 * w23 + v02 * w45 + v03 * w67;
        v2f av1 = v10 * w01 + v11 * w23 + v12 * w45 + v13 * w67;
        v2f av2 = v20 * w01 + v21 * w23 + v22 * w45 + v23 * w67;
        v2f av3 = v30 * w01 + v31 * w23 + v32 * w45 + v33 * w67;
        float p0 = ok0 ? __expf(leaky02(av0.x + av0.y + adh)) : 0.f;
        float p1 = ok1 ? __expf(leaky02(av1.x + av1.y + adh)) : 0.f;
        float p2 = ok2 ? __expf(leaky02(av2.x + av2.y + adh)) : 0.f;
        float p3 = ok3 ? __expf(leaky02(av3.x + av3.y + adh)) : 0.f;
        d += (p0 + p1) + (p2 + p3);
        acc0 += v00 * p0; acc1 += v01 * p0; acc2 += v02 * p0; acc3 += v03 * p0;
        acc0 += v10 * p1; acc1 += v11 * p1; acc2 += v12 * p1; acc3 += v13 * p1;
        acc0 += v20 * p2; acc1 += v21 * p2; acc2 += v22 * p2; acc3 += v23 * p2;
        acc0 += v30 * p3; acc1 += v31 * p3; acc2 += v32 * p3; acc3 += v33 * p3;
    }
    // reduce over the 8 slot-lanes (lane bits 3..5)
#pragma unroll
    for (int off = 8; off < 64; off <<= 1) {
        d += __shfl_xor(d, off);
        acc0.x += __shfl_xor(acc0.x, off); acc0.y += __shfl_xor(acc0.y, off);
        acc1.x += __shfl_xor(acc1.x, off); acc1.y += __shfl_xor(acc1.y, off);
        acc2.x += __shfl_xor(acc2.x, off); acc2.y += __shfl_xor(acc2.y, off);
        acc3.x += __shfl_xor(acc3.x, off); acc3.y += __shfl_xor(acc3.y, off);
    }
    float vals[8] = {acc0.x, acc0.y, acc1.x, acc1.y, acc2.x, acc2.y, acc3.x, acc3.y};
    float hv = vals[0];
#pragma unroll
    for (int c = 1; c < 8; ++c) hv = ((int)slot == c) ? vals[c] : hv;
    int f = (int)(h * 8u + slot);
    hv = hv / (d + 1e-16f) + b1[f];
    hv = hv > 0.f ? hv : __expf(hv) - 1.0f;          // ELU
    // permute so lane stores feature f' = lane (contiguous 2B stores)
    float hvp = __shfl(hv, ((lane & 7) << 3) | (lane >> 3));
    h1[(unsigned)node * 64u + (unsigned)lane] = __float2bfloat16(hvp);
}

// ---------- layer-2 GEMM: h1[N,64](bf16) @ W2[64,8] + adst2 scalar ----------
__global__ __launch_bounds__(256) void gemm2h_kernel(const __hip_bfloat16* __restrict__ h1,
                                                     const float* __restrict__ W2,
                                                     const float* __restrict__ a2d,
                                                     __hip_bfloat16* __restrict__ xh2,
                                                     float* __restrict__ adst2, int N) {
    __shared__ float w2s[512];
    __shared__ float aa[8];
    int tid = threadIdx.x;
    for (int i = tid; i < 512; i += 256) w2s[i] = W2[i];
    if (tid < 8) aa[tid] = a2d[tid];
    __syncthreads();
    unsigned n = blockIdx.x * 256u + (unsigned)tid;
    if (n >= (unsigned)N) return;
    const uint4* hp = (const uint4*)h1 + n * 8u;
    float q[8] = {};
#pragma unroll
    for (int j = 0; j < 8; ++j) {
        uint4 u = hp[j];
        float hv[8] = {bflo(u.x), bfhi(u.x), bflo(u.y), bfhi(u.y),
                       bflo(u.z), bfhi(u.z), bflo(u.w), bfhi(u.w)};
#pragma unroll
        for (int e = 0; e < 8; ++e) {
            int f = j * 8 + e;
            float4 wa = *(const float4*)&w2s[f * 8];
            float4 wb = *(const float4*)&w2s[f * 8 + 4];
            q[0] += hv[e] * wa.x; q[1] += hv[e] * wa.y;
            q[2] += hv[e] * wa.z; q[3] += hv[e] * wa.w;
            q[4] += hv[e] * wb.x; q[5] += hv[e] * wb.y;
            q[6] += hv[e] * wb.z; q[7] += hv[e] * wb.w;
        }
    }
    uint4 o;
    o.x = (unsigned)f2bf(q[0]) | ((unsigned)f2bf(q[1]) << 16);
    o.y = (unsigned)f2bf(q[2]) | ((unsigned)f2bf(q[3]) << 16);
    o.z = (unsigned)f2bf(q[4]) | ((unsigned)f2bf(q[5]) << 16);
    o.w = (unsigned)f2bf(q[6]) | ((unsigned)f2bf(q[7]) << 16);
    *((uint4*)xh2 + n) = o;
    float d2 = 0.f;
#pragma unroll
    for (int c = 0; c < 8; ++c) d2 += q[c] * aa[c];
    adst2[n] = d2;
}

// ---------- layer-2 aggregate (a_src2 recomputed) + bias + fused mean-pool ----------
__global__ __launch_bounds__(256) void agg2_pool_kernel(const int* __restrict__ rowptr,
                                                        const int* __restrict__ esrc,
                                                        const float* __restrict__ a2s,
                                                        const float* __restrict__ adst2,
                                                        const __hip_bfloat16* __restrict__ xh2,
                                                        const float* __restrict__ b2,
                                                        const int* __restrict__ batch,
                                                        float* __restrict__ pool,
                                                        float* __restrict__ cnt, int N, int B) {
    __shared__ float ps[64 * 8];
    __shared__ float cs[64];
    int tid = threadIdx.x;
    for (int i = tid; i < 512; i += 256) ps[i] = 0.f;
    if (tid < 64) cs[tid] = 0.f;
    __syncthreads();
    int node = blockIdx.x * 32 + (tid >> 3);
    int slot = tid & 7;
    if (node < N) {
        float adh = adst2[node];
        v2f w01 = {a2s[0], a2s[1]}, w23 = {a2s[2], a2s[3]};
        v2f w45 = {a2s[4], a2s[5]}, w67 = {a2s[6], a2s[7]};
        unsigned start = (unsigned)rowptr[node];
        int len = rowptr[node + 1] - (int)start;
        const uint4* x4 = (const uint4*)xh2;
        float d = 0.f;
        v2f acc0 = {0.f, 0.f}, acc1 = {0.f, 0.f}, acc2 = {0.f, 0.f}, acc3 = {0.f, 0.f};
        for (int kb = 0; kb < len; kb += 32) {
            int k0 = kb + slot;
            bool ok0 = k0 < len, ok1 = k0 + 8 < len, ok2 = k0 + 16 < len, ok3 = k0 + 24 < len;
            unsigned s0 = ok0 ? (unsigned)esrc[start + k0] : 0u;
            unsigned s1 = ok1 ? (unsigned)esrc[start + k0 + 8] : 0u;
            unsigned s2 = ok2 ? (unsigned)esrc[start + k0 + 16] : 0u;
            unsigned s3 = ok3 ? (unsigned)esrc[start + k0 + 24] : 0u;
            uint4 u0 = x4[s0];
            uint4 u1 = x4[s1];
            uint4 u2 = x4[s2];
            uint4 u3 = x4[s3];
            v2f v00 = bf2(u0.x), v01 = bf2(u0.y), v02 = bf2(u0.z), v03 = bf2(u0.w);
            v2f v10 = bf2(u1.x), v11 = bf2(u1.y), v12 = bf2(u1.z), v13 = bf2(u1.w);
            v2f v20 = bf2(u2.x), v21 = bf2(u2.y), v22 = bf2(u2.z), v23 = bf2(u2.w);
            v2f v30 = bf2(u3.x), v31 = bf2(u3.y), v32 = bf2(u3.z), v33 = bf2(u3.w);
            v2f av0 = v00 * w01 + v01 * w23 + v02 * w45 + v03 * w67;
            v2f av1 = v10 * w01 + v11 * w23 + v12 * w45 + v13 * w67;
            v2f av2 = v20 * w01 + v21 * w23 + v22 * w45 + v23 * w67;
            v2f av3 = v30 * w01 + v31 * w23 + v32 * w45 + v33 * w67;
            float p0 = ok0 ? __expf(leaky02(av0.x + av0.y + adh)) : 0.f;
            float p1 = ok1 ? __expf(leaky02(av1.x + av1.y + adh)) : 0.f;
            float p2 = ok2 ? __expf(leaky02(av2.x + av2.y + adh)) : 0.f;
            float p3 = ok3 ? __expf(leaky02(av3.x + av3.y + adh)) : 0.f;
            d += (p0 + p1) + (p2 + p3);
            acc0 += v00 * p0; acc1 += v01 * p0; acc2 += v02 * p0; acc3 += v03 * p0;
            acc0 += v10 * p1; acc1 += v11 * p1; acc2 += v12 * p1; acc3 += v13 * p1;
            acc0 += v20 * p2; acc1 += v21 * p2; acc2 += v22 * p2; acc3 += v23 * p2;
            acc0 += v30 * p3; acc1 += v31 * p3; acc2 += v32 * p3; acc3 += v33 * p3;
        }
#pragma unroll
        for (int off = 1; off < 8; off <<= 1) {
            d += __shfl_xor(d, off);
            acc0.x += __shfl_xor(acc0.x, off); acc0.y += __shfl_xor(acc0.y, off);
            acc1.x += __shfl_xor(acc1.x, off); acc1.y += __shfl_xor(acc1.y, off);
            acc2.x += __shfl_xor(acc2.x, off); acc2.y += __shfl_xor(acc2.y, off);
            acc3.x += __shfl_xor(acc3.x, off); acc3.y += __shfl_xor(acc3.y, off);
        }
        float vals[8] = {acc0.x, acc0.y, acc1.x, acc1.y, acc2.x, acc2.y, acc3.x, acc3.y};
        float v = vals[0];
#pragma unroll
        for (int c = 1; c < 8; ++c) v = (slot == c) ? vals[c] : v;
        v = v / (d + 1e-16f) + b2[slot];
        int b = batch[node];
        atomicAdd(&ps[b * 8 + slot], v);
        if (slot == 0) atomicAdd(&cs[b], 1.0f);
    }
    __syncthreads();
    for (int i = tid; i < 512; i += 256)
        if (ps[i] != 0.f) atomicAdd(&pool[i], ps[i]);
    if (tid < 64 && cs[tid] != 0.f) atomicAdd(&cnt[tid], cs[tid]);
}

__global__ __launch_bounds__(256) void final_kernel(const float* __restrict__ pool,
                                                    const float* __restrict__ cnt,
                                                    float* __restrict__ out, int B) {
    int idx = blockIdx.x * 256 + threadIdx.x;
    if (idx >= B * 8) return;
    out[idx] = pool[idx] / fmaxf(cnt[idx >> 3], 1.0f);
}

extern "C" void kernel_launch(void* const* d_in, const int* in_sizes, int n_in,
                              void* d_out, int out_size, void* d_ws, size_t ws_size,
                              hipStream_t stream) {
    const float* x   = (const float*)d_in[0];
    const int*   ei  = (const int*)d_in[1];
    const int*   bat = (const int*)d_in[2];
    const float* W1  = (const float*)d_in[3];
    const float* a1s = (const float*)d_in[4];
    const float* a1d = (const float*)d_in[5];
    const float* b1  = (const float*)d_in[6];
    const float* W2  = (const float*)d_in[7];
    const float* a2s = (const float*)d_in[8];
    const float* a2d = (const float*)d_in[9];
    const float* b2  = (const float*)d_in[10];
    float* out = (float*)d_out;

    const int N = in_sizes[0] / 128;
    const int E = in_sizes[1] / 2;
    const int B = out_size / 8;
    const int Etot = E + N;
    const int NB = (N + BIN_NODES - 1) / BIN_NODES;
    const int NBB = (Etot + 512 * EPT - 1) / (512 * EPT);   // binB blocks
    const int NG = (N + 63) / 64;                           // gemm blocks

    // ---- workspace layout (float slots) ----
    float* wsp = (float*)d_ws;
    __hip_bfloat16* xh1 = (__hip_bfloat16*)wsp;                       // 64N bf16 = 32N fl
    float* adst1  = wsp + (size_t)N * 32;                             // 8N
    __hip_bfloat16* h1 = (__hip_bfloat16*)(adst1 + (size_t)N * 8);    // 64N bf16 = 32N fl
    __hip_bfloat16* xh2 = (__hip_bfloat16*)(adst1 + (size_t)N * 40);  // 8N bf16 = 4N fl
    float* adst2  = adst1 + (size_t)N * 44;                           // N
    int*   rowptr = (int*)(adst2 + (size_t)N);                        // N+1 (+pad)
    int*   esrc   = rowptr + (size_t)N + 8;                           // Etot
    unsigned* binned = (unsigned*)(esrc + (size_t)Etot);              // NB*BIN_CAP
    // ---- zero-init region ----
    int*   cur    = (int*)(binned + (size_t)NB * BIN_CAP);            // NB
    float* pool   = (float*)(cur + NB);                               // 8B
    float* cnt    = pool + (size_t)B * 8;                             // B
    size_t zbytes = ((size_t)NB + 9 * (size_t)B) * 4;
    hipMemsetAsync(cur, 0, zbytes, stream);

    k1_kernel<<<dim3(NBB + NG), dim3(512), 0, stream>>>(x, W1, a1d, ei,
                                                        xh1, adst1,
                                                        cur, binned, N, E, Etot, NB, NBB);
    binC_kernel<<<dim3(NB), dim3(256), 0, stream>>>(cur, binned, rowptr, esrc, N, Etot, NB);
    agg1_kernel<<<dim3((N + 3) / 4), dim3(256), 0, stream>>>(rowptr, esrc, a1s, adst1, xh1, b1, h1, N);
    gemm2h_kernel<<<dim3((N + 255) / 256), dim3(256), 0, stream>>>(h1, W2, a2d, xh2, adst2, N);
    agg2_pool_kernel<<<dim3((N + 31) / 32), dim3(256), 0, stream>>>(rowptr, esrc, a2s, adst2,
                                                                    xh2, b2, bat, pool, cnt, N, B);
    final_kernel<<<dim3((B * 8 + 255) / 256), dim3(256), 0, stream>>>(pool, cnt, out, B);
}